// Round 9
// baseline (436.863 us; speedup 1.0000x reference)
//
#include <hip/hip_runtime.h>
#include <stdint.h>

typedef unsigned short u16;
typedef unsigned int   u32;

#define N_NODES  100000
#define N_EDGES  1600000
#define DFEAT    128
#define N_GRAPHS 512

#define NBKT   391    // buckets of 256 nodes (ceil(N/256))
#define EPB    8192   // edges per block in hist/scatter
#define NBLK_E 196    // ceil(N_EDGES/EPB)
#define LBUF   8192   // per-bucket capacity (mean 4096, sigma ~64)
#define GB     782    // gemm1 blocks (128 rows each)

typedef float f32x4 __attribute__((ext_vector_type(4)));
typedef short s16x8 __attribute__((ext_vector_type(8)));

__device__ __forceinline__ float bflo(u32 u) { return __uint_as_float(u << 16); }
__device__ __forceinline__ float bfhi(u32 u) { return __uint_as_float(u & 0xffff0000u); }
__device__ __forceinline__ u16 f2bf(float f) {
  u32 u = __float_as_uint(f);
  return (u16)((u + 0x7fffu + ((u >> 16) & 1u)) >> 16);   // RNE
}
__device__ __forceinline__ u32 pack2(float f0, float f1) {
  return (u32)f2bf(f0) | ((u32)f2bf(f1) << 16);
}

__device__ __forceinline__ int ld_src(const int* ei, int m, int e) {
  return m ? ei[2 * e] : ei[e];
}
__device__ __forceinline__ int ld_dst(const int* ei, int m, int e) {
  return m ? ei[2 * (N_EDGES + e)] : ei[N_EDGES + e];
}

// block-local int64-vs-int32 detect (odd words of first 64 edge slots all zero <=> int64)
__device__ __forceinline__ int detect_m_block(const int* __restrict__ ei, int* sm) {
  int t = threadIdx.x;
  if (t < 64) {
    int v = ei[2 * t + 1];
    unsigned long long b = __ballot(v != 0);
    if (t == 0) *sm = (b == 0ull) ? 1 : 0;
  }
  __syncthreads();
  return *sm;
}

#define LP 136   // LDS pitch in ushorts (272B, 16B-aligned rows)

// ---------------- mega pass: gemm1 (unscaled) + edge histogram + W cvt + flag ----
__global__ __launch_bounds__(256) void mega_k(const float* __restrict__ x,
                                              const int* __restrict__ ei,
                                              int* __restrict__ ghist,
                                              const float* __restrict__ W1,
                                              const float* __restrict__ W2,
                                              const float* __restrict__ W3,
                                              u16* __restrict__ T2, u16* __restrict__ T3,
                                              int* __restrict__ flag,
                                              u16* __restrict__ Y) {
  __shared__ u16 sX[128 * LP];
  __shared__ u16 sW[128 * LP];
  __shared__ int hist[NBKT];
  __shared__ int sm;
  int tid = threadIdx.x, b = blockIdx.x;

  if (b < GB) {
    // ---- gemm1: Y = bf16(X @ W1), NOT dinv-scaled (dinv not ready yet) ----
    int r0 = b * 128;
    // stage W1 with transpose+convert: sW[n*LP + k] = bf16(W1[k][n])
    for (int c = tid; c < 2048; c += 256) {
      int n = c & 127, k0 = (c >> 7) * 8;
#pragma unroll
      for (int j = 0; j < 8; j++)
        sW[n * LP + k0 + j] = f2bf(W1[(size_t)(k0 + j) * DFEAT + n]);
    }
    // stage X f32 -> bf16
    for (int c = tid; c < 2048; c += 256) {
      int row = c >> 4, off = (c & 15) * 8;
      int grow = r0 + row;
      uint4 o = make_uint4(0, 0, 0, 0);
      if (grow < N_NODES) {
        const float* px = x + (size_t)grow * DFEAT + off;
        float4 v0 = *(const float4*)px;
        float4 v1 = *(const float4*)(px + 4);
        o.x = pack2(v0.x, v0.y); o.y = pack2(v0.z, v0.w);
        o.z = pack2(v1.x, v1.y); o.w = pack2(v1.z, v1.w);
      }
      *(uint4*)(&sX[row * LP + off]) = o;
    }
    __syncthreads();

    int wave = tid >> 6, lane = tid & 63;
    int q = lane >> 4, r = lane & 15;
    int wr0 = wave * 32;

    f32x4 acc[2][8];
#pragma unroll
    for (int m = 0; m < 2; m++)
#pragma unroll
      for (int i = 0; i < 8; i++) acc[m][i] = (f32x4){0.f, 0.f, 0.f, 0.f};

#pragma unroll
    for (int kk = 0; kk < 4; kk++) {
      int k0 = kk * 32;
      s16x8 a0 = *(const s16x8*)(&sX[(wr0 + r) * LP + k0 + q * 8]);
      s16x8 a1 = *(const s16x8*)(&sX[(wr0 + 16 + r) * LP + k0 + q * 8]);
#pragma unroll
      for (int nt = 0; nt < 8; nt++) {
        s16x8 bb = *(const s16x8*)(&sW[(nt * 16 + r) * LP + k0 + q * 8]);
        acc[0][nt] = __builtin_amdgcn_mfma_f32_16x16x32_bf16(a0, bb, acc[0][nt], 0, 0, 0);
        acc[1][nt] = __builtin_amdgcn_mfma_f32_16x16x32_bf16(a1, bb, acc[1][nt], 0, 0, 0);
      }
    }

#pragma unroll
    for (int m = 0; m < 2; m++) {
#pragma unroll
      for (int i = 0; i < 4; i++) {
        int grow = r0 + wr0 + m * 16 + q * 4 + i;
        if (grow < N_NODES) {
#pragma unroll
          for (int nt = 0; nt < 8; nt++)
            Y[(size_t)grow * DFEAT + nt * 16 + r] = f2bf(acc[m][nt][i]);
        }
      }
    }
    return;
  }

  if (b < GB + NBLK_E) {
    // ---- edge histogram over buckets ----
    int hb = b - GB;
    int m = detect_m_block(ei, &sm);
    for (int i = tid; i < NBKT; i += 256) hist[i] = 0;
    __syncthreads();
    int e0 = hb * EPB;
#pragma unroll
    for (int p = 0; p < EPB / 256; p++) {
      int e = e0 + p * 256 + tid;
      if (e < N_EDGES) atomicAdd(&hist[ld_dst(ei, m, e) >> 8], 1);
    }
    __syncthreads();
    for (int i = tid; i < NBKT; i += 256) ghist[hb * NBKT + i] = hist[i];
    return;
  }

  int r = b - GB - NBLK_E;
  if (r < 2) {   // W2/W3 transpose+convert
    const float* W = (r == 0) ? W2 : W3;
    u16* T         = (r == 0) ? T2 : T3;
    for (int i = tid; i < DFEAT * DFEAT; i += 256) {
      int n = i >> 7, k = i & 127;
      T[i] = f2bf(W[k * DFEAT + n]);
    }
  } else {       // flag for pool_k
    if (tid < 64) {
      int v = ei[2 * tid + 1];
      unsigned long long mm = __ballot(v != 0);
      if (tid == 0) *flag = (mm == 0ull) ? 1 : 0;
    }
  }
}

// exclusive scan of LDS array arr[NBKT] -> bb[NBKT+1] (256 threads)
__device__ __forceinline__ void scan_lds391(const int* arr, int* bb, int* sc) {
  int t = threadIdx.x;
  int v0 = arr[t];
  sc[t] = v0;
  for (int off = 1; off < 256; off <<= 1) {
    __syncthreads(); int add = (t >= off) ? sc[t - off] : 0;
    __syncthreads(); sc[t] += add;
  }
  __syncthreads();
  bb[t] = sc[t] - v0;
  int base256 = sc[255];
  __syncthreads();
  int v1 = (t < NBKT - 256) ? arr[256 + t] : 0;
  sc[t] = v1;
  for (int off = 1; off < 256; off <<= 1) {
    __syncthreads(); int add = (t >= off) ? sc[t - off] : 0;
    __syncthreads(); sc[t] += add;
  }
  __syncthreads();
  if (t < NBKT - 256) bb[256 + t] = base256 + sc[t] - v1;
  if (t == 0) bb[NBKT] = N_EDGES;
  __syncthreads();
}

// ---------------- pass C: place edges into bucket regions (inline prefix) --------
__global__ __launch_bounds__(256) void scatterC_k(const int* __restrict__ ei,
                                                  const int* __restrict__ ghist,
                                                  u32* __restrict__ colpk) {
  __shared__ int sm;
  __shared__ int colsum[NBKT];
  __shared__ int colpre[NBKT];
  __shared__ int cur[NBKT];
  __shared__ int bb[NBKT + 1];
  __shared__ int sc[256];
  int t = threadIdx.x, b = blockIdx.x;
  int m = detect_m_block(ei, &sm);
  // column totals + prefix over blocks < b
  for (int k = t; k < NBKT; k += 256) {
    int tot = 0, pre = 0;
    for (int b2 = 0; b2 < NBLK_E; b2++) {
      int v = ghist[b2 * NBKT + k];
      tot += v;
      pre += (b2 < b) ? v : 0;
    }
    colsum[k] = tot; colpre[k] = pre;
  }
  __syncthreads();
  scan_lds391(colsum, bb, sc);
  for (int k = t; k < NBKT; k += 256) cur[k] = bb[k] + colpre[k];
  __syncthreads();
  int e0 = b * EPB;
#pragma unroll
  for (int p = 0; p < EPB / 256; p++) {
    int e = e0 + p * 256 + t;
    if (e < N_EDGES) {
      int d = ld_dst(ei, m, e);
      int s = ld_src(ei, m, e);
      int pos = atomicAdd(&cur[d >> 8], 1);
      colpk[pos] = (u32)s | ((u32)(d & 255) << 24);
    }
  }
}

// ---------------- pass D: degrees, rowptr, dinv, exact CSR placement ----------------
__global__ __launch_bounds__(256) void fillD_k(const int* __restrict__ ghist,
                                               const u32* __restrict__ colpk,
                                               int* __restrict__ colarr,
                                               int* __restrict__ rowptr,
                                               float* __restrict__ dinv) {
  __shared__ int hist[256];
  __shared__ int cur[256];
  __shared__ int lbuf[LBUF];
  __shared__ int colsum[NBKT];
  __shared__ int bb[NBKT + 1];
  __shared__ int sc[256];
  int t = threadIdx.x, b = blockIdx.x;
  for (int k = t; k < NBKT; k += 256) {
    int tot = 0;
    for (int b2 = 0; b2 < NBLK_E; b2++) tot += ghist[b2 * NBKT + k];
    colsum[k] = tot;
  }
  __syncthreads();
  scan_lds391(colsum, bb, sc);
  int base = bb[b], end = bb[b + 1], cnt = end - base;
  hist[t] = 0;
  __syncthreads();
  for (int i = t; i < cnt; i += 256) atomicAdd(&hist[colpk[base + i] >> 24], 1);
  __syncthreads();
  int c = hist[t];
  cur[t] = c;
  for (int off = 1; off < 256; off <<= 1) {
    __syncthreads(); int add = (t >= off) ? cur[t - off] : 0;
    __syncthreads(); cur[t] += add;
  }
  __syncthreads();
  int excl = cur[t] - c;
  int node = b * 256 + t;
  if (node < N_NODES) {
    rowptr[node] = base + excl;
    dinv[node] = rsqrtf((float)(c + 1));      // +1 self-loop
  }
  if (b == NBKT - 1 && t == 0) rowptr[N_NODES] = N_EDGES;
  __syncthreads();
  cur[t] = excl;
  __syncthreads();
  for (int i = t; i < cnt; i += 256) {
    u32 v = colpk[base + i];
    int slot = atomicAdd(&cur[v >> 24], 1);
    if (slot < LBUF) lbuf[slot] = (int)(v & 0x00FFFFFFu);
  }
  __syncthreads();
  for (int i = t; i < cnt; i += 256) colarr[base + i] = lbuf[i];
}

// ---------------- gather-accumulate ----------------
struct Acc8 {
  float a0, a1, a2, a3, a4, a5, a6, a7;
  __device__ __forceinline__ void zero() {
    a0 = a1 = a2 = a3 = a4 = a5 = a6 = a7 = 0.f;
  }
  __device__ __forceinline__ void addv(uint4 v) {
    a0 += bflo(v.x); a1 += bfhi(v.x); a2 += bflo(v.y); a3 += bfhi(v.y);
    a4 += bflo(v.z); a5 += bfhi(v.z); a6 += bflo(v.w); a7 += bfhi(v.w);
  }
  __device__ __forceinline__ void fmav(uint4 v, float s) {
    a0 = fmaf(bflo(v.x), s, a0); a1 = fmaf(bfhi(v.x), s, a1);
    a2 = fmaf(bflo(v.y), s, a2); a3 = fmaf(bfhi(v.y), s, a3);
    a4 = fmaf(bflo(v.z), s, a4); a5 = fmaf(bfhi(v.z), s, a5);
    a6 = fmaf(bflo(v.w), s, a6); a7 = fmaf(bfhi(v.w), s, a7);
  }
};

// plain gather: sources already dinv-scaled
__device__ __forceinline__ Acc8 gather_plain(const u32* __restrict__ HS,
                                             int s, int e, int node, int fp,
                                             const int* __restrict__ colidx) {
  Acc8 A; A.zero();
  A.addv(*(const uint4*)(HS + (size_t)node * 64 + fp * 4));
  int j = s;
  for (; j + 4 <= e; j += 4) {
    int i0 = colidx[j], i1 = colidx[j + 1], i2 = colidx[j + 2], i3 = colidx[j + 3];
    uint4 w0 = *(const uint4*)(HS + (size_t)i0 * 64 + fp * 4);
    uint4 w1 = *(const uint4*)(HS + (size_t)i1 * 64 + fp * 4);
    uint4 w2 = *(const uint4*)(HS + (size_t)i2 * 64 + fp * 4);
    uint4 w3 = *(const uint4*)(HS + (size_t)i3 * 64 + fp * 4);
    A.addv(w0); A.addv(w1); A.addv(w2); A.addv(w3);
  }
  for (; j < e; j++) {
    A.addv(*(const uint4*)(HS + (size_t)colidx[j] * 64 + fp * 4));
  }
  return A;
}

// scaled gather: multiply each source row by dinv[src] (layer-1: HS unscaled)
__device__ __forceinline__ Acc8 gather_scaled(const u32* __restrict__ HS,
                                              const float* __restrict__ dinv,
                                              int s, int e, int node, int fp,
                                              const int* __restrict__ colidx) {
  Acc8 A; A.zero();
  A.fmav(*(const uint4*)(HS + (size_t)node * 64 + fp * 4), dinv[node]);
  int j = s;
  for (; j + 4 <= e; j += 4) {
    int i0 = colidx[j], i1 = colidx[j + 1], i2 = colidx[j + 2], i3 = colidx[j + 3];
    float s0 = dinv[i0], s1 = dinv[i1], s2 = dinv[i2], s3 = dinv[i3];
    uint4 w0 = *(const uint4*)(HS + (size_t)i0 * 64 + fp * 4);
    uint4 w1 = *(const uint4*)(HS + (size_t)i1 * 64 + fp * 4);
    uint4 w2 = *(const uint4*)(HS + (size_t)i2 * 64 + fp * 4);
    uint4 w3 = *(const uint4*)(HS + (size_t)i3 * 64 + fp * 4);
    A.fmav(w0, s0); A.fmav(w1, s1); A.fmav(w2, s2); A.fmav(w3, s3);
  }
  for (; j < e; j++) {
    int i0 = colidx[j];
    A.fmav(*(const uint4*)(HS + (size_t)i0 * 64 + fp * 4), dinv[i0]);
  }
  return A;
}

// ---------------- fused agg(layer i) + row-GEMM(layer i+1) ----------------
// 16 nodes/block. Gather -> relu(dinv*sum+bias) -> bf16 LDS (4KB) -> MFMA with
// B-fragments straight from global W (32KB, L1-resident) -> dinv-scale -> Y.
__global__ __launch_bounds__(256) void aggmm_k(const u32* __restrict__ HS,
                                               const float* __restrict__ dinv,
                                               const int* __restrict__ rowptr,
                                               const int* __restrict__ colidx,
                                               const float* __restrict__ bias,
                                               const u16* __restrict__ Wt,
                                               u16* __restrict__ Y,
                                               int src_scaled) {
  __shared__ u16 sX[16 * LP];
  int t = threadIdx.x;
  int r0b = blockIdx.x * 16;     // grid 6250 -> exactly N_NODES
  int lrow = t >> 4, fp = t & 15;
  int node = r0b + lrow;
  int s = rowptr[node], e = rowptr[node + 1];

  Acc8 A;
  if (src_scaled) A = gather_plain(HS, s, e, node, fp, colidx);
  else            A = gather_scaled(HS, dinv, s, e, node, fp, colidx);

  float dv = dinv[node];
  float4 b0 = *(const float4*)(bias + fp * 8);
  float4 b1 = *(const float4*)(bias + fp * 8 + 4);
  float r0f = fmaxf(A.a0 * dv + b0.x, 0.f), r1f = fmaxf(A.a1 * dv + b0.y, 0.f);
  float r2f = fmaxf(A.a2 * dv + b0.z, 0.f), r3f = fmaxf(A.a3 * dv + b0.w, 0.f);
  float r4f = fmaxf(A.a4 * dv + b1.x, 0.f), r5f = fmaxf(A.a5 * dv + b1.y, 0.f);
  float r6f = fmaxf(A.a6 * dv + b1.z, 0.f), r7f = fmaxf(A.a7 * dv + b1.w, 0.f);
  uint4 o;
  o.x = pack2(r0f, r1f); o.y = pack2(r2f, r3f);
  o.z = pack2(r4f, r5f); o.w = pack2(r6f, r7f);
  *(uint4*)(&sX[lrow * LP + fp * 8]) = o;
  __syncthreads();

  // row-GEMM: 16 rows x 128 cols, K=128; wave handles 2 N-tiles
  int wave = t >> 6, lane = t & 63;
  int q = lane >> 4, r = lane & 15;
  int nt0 = wave * 2, nt1 = wave * 2 + 1;

  f32x4 acc0 = (f32x4){0.f, 0.f, 0.f, 0.f};
  f32x4 acc1 = (f32x4){0.f, 0.f, 0.f, 0.f};
#pragma unroll
  for (int kk = 0; kk < 4; kk++) {
    int k0 = kk * 32;
    s16x8 a  = *(const s16x8*)(&sX[r * LP + k0 + q * 8]);
    s16x8 w0 = *(const s16x8*)(Wt + (size_t)(nt0 * 16 + r) * DFEAT + k0 + q * 8);
    s16x8 w1 = *(const s16x8*)(Wt + (size_t)(nt1 * 16 + r) * DFEAT + k0 + q * 8);
    acc0 = __builtin_amdgcn_mfma_f32_16x16x32_bf16(a, w0, acc0, 0, 0, 0);
    acc1 = __builtin_amdgcn_mfma_f32_16x16x32_bf16(a, w1, acc1, 0, 0, 0);
  }
#pragma unroll
  for (int i = 0; i < 4; i++) {
    int grow = r0b + q * 4 + i;
    float dvv = dinv[grow];
    Y[(size_t)grow * DFEAT + nt0 * 16 + r] = f2bf(acc0[i] * dvv);
    Y[(size_t)grow * DFEAT + nt1 * 16 + r] = f2bf(acc1[i] * dvv);
  }
}

// ---------------- standalone aggregation (layer-3 epilogue) ----------------
__global__ __launch_bounds__(256) void agg_k(const u32* __restrict__ HS,
                                             const float* __restrict__ dinv,
                                             const int* __restrict__ rowptr,
                                             const int* __restrict__ colidx,
                                             const float* __restrict__ bias,
                                             u32* __restrict__ OUT) {
  int t = threadIdx.x;
  int node = blockIdx.x * 16 + (t >> 4);   // grid 6250 -> exactly N_NODES
  int fp = t & 15;
  int s = rowptr[node], e = rowptr[node + 1];

  Acc8 A = gather_plain(HS, s, e, node, fp, colidx);

  float dv = dinv[node];
  float4 b0 = *(const float4*)(bias + fp * 8);
  float4 b1 = *(const float4*)(bias + fp * 8 + 4);
  uint4 o;
  o.x = pack2(A.a0 * dv + b0.x, A.a1 * dv + b0.y);
  o.y = pack2(A.a2 * dv + b0.z, A.a3 * dv + b0.w);
  o.z = pack2(A.a4 * dv + b1.x, A.a5 * dv + b1.y);
  o.w = pack2(A.a6 * dv + b1.z, A.a7 * dv + b1.w);
  *(uint4*)(OUT + (size_t)node * 64 + fp * 4) = o;
}

// ---------------- pooling: mean over sorted batch ranges ----------------
__device__ __forceinline__ int lower_bound_i(const int* a, int n, int key, int shift) {
  int lo = 0, hi = n;
  while (lo < hi) {
    int mid = (lo + hi) >> 1;
    if (a[mid << shift] < key) lo = mid + 1; else hi = mid;
  }
  return lo;
}

__global__ __launch_bounds__(256) void pool_k(const u32* __restrict__ H,
                                              const int* __restrict__ batch,
                                              const int* __restrict__ flag,
                                              float* __restrict__ OUT) {
  int g = blockIdx.x;
  int m = *flag;   // 1 if int64 batch
  int lo = lower_bound_i(batch, N_NODES, g, m);
  int hi = lower_bound_i(batch, N_NODES, g + 1, m);
  int cnt = hi - lo;
  int d2 = threadIdx.x & 63;
  int half = threadIdx.x >> 6;
  float a0 = 0.f, a1 = 0.f;
  for (int row = lo + half; row < hi; row += 4) {
    u32 v = H[(size_t)row * 64 + d2];
    a0 += bflo(v); a1 += bfhi(v);
  }
  __shared__ float red0[256], red1[256];
  red0[threadIdx.x] = a0; red1[threadIdx.x] = a1;
  __syncthreads();
  if (threadIdx.x < 64) {
    float s0 = red0[d2] + red0[d2 + 64] + red0[d2 + 128] + red0[d2 + 192];
    float s1 = red1[d2] + red1[d2 + 64] + red1[d2 + 128] + red1[d2 + 192];
    float inv = 1.0f / fmaxf((float)cnt, 1.0f);
    OUT[g * DFEAT + 2 * d2]     = s0 * inv;
    OUT[g * DFEAT + 2 * d2 + 1] = s1 * inv;
  }
}

// ---------------- orchestration (7 dispatches) ----------------

extern "C" void kernel_launch(void* const* d_in, const int* in_sizes, int n_in,
                              void* d_out, int out_size, void* d_ws, size_t ws_size,
                              hipStream_t stream) {
  const float* x   = (const float*)d_in[0];
  const int* ei    = (const int*)d_in[1];
  const int* batch = (const int*)d_in[2];
  const float* W1  = (const float*)d_in[3];
  const float* b1  = (const float*)d_in[4];
  const float* W2  = (const float*)d_in[5];
  const float* b2  = (const float*)d_in[6];
  const float* W3  = (const float*)d_in[7];
  const float* b3  = (const float*)d_in[8];
  float* out = (float*)d_out;

  char* p = (char*)d_ws;
  size_t off = 0;
  auto carve = [&](size_t bytes) -> void* {
    void* q = p + off;
    off = (off + bytes + 255) & ~(size_t)255;
    return q;
  };
  int*   flag   = (int*)carve(256);
  int*   ghist  = (int*)carve((size_t)NBLK_E * NBKT * 4);
  int*   rowptr = (int*)carve((N_NODES + 1) * 4);
  float* dinv   = (float*)carve(N_NODES * 4);
  u32*   colpk  = (u32*)carve((size_t)N_EDGES * 4);
  int*   colarr = (int*)carve((size_t)N_EDGES * 4);
  u16*   Wt2    = (u16*)carve(DFEAT * DFEAT * 2);
  u16*   Wt3    = (u16*)carve(DFEAT * DFEAT * 2);
  u32*   bufA   = (u32*)carve((size_t)N_NODES * 64 * 4);
  u32*   bufB   = (u32*)carve((size_t)N_NODES * 64 * 4);
  (void)ws_size;

  const int AB = N_NODES / 16;            // 6250

  // 1: gemm1(X@W1, unscaled) + histogram + W2/W3 cvt + flag
  mega_k<<<GB + NBLK_E + 3, 256, 0, stream>>>(x, ei, ghist, W1, W2, W3, Wt2, Wt3,
                                              flag, (u16*)bufA);
  // 2: bucket scatter (inline prefix scan)
  scatterC_k<<<NBLK_E, 256, 0, stream>>>(ei, ghist, colpk);
  // 3: CSR finalize + degrees + dinv
  fillD_k<<<NBKT, 256, 0, stream>>>(ghist, colpk, colarr, rowptr, dinv);
  // 4: agg(L1, src-scaled gather) + relu + row-GEMM W2 -> bufB (dinv-scaled)
  aggmm_k<<<AB, 256, 0, stream>>>(bufA, dinv, rowptr, colarr, b1, Wt2, (u16*)bufB, 0);
  // 5: agg(L2) + relu + row-GEMM W3 -> bufA (dinv-scaled)
  aggmm_k<<<AB, 256, 0, stream>>>(bufB, dinv, rowptr, colarr, b2, Wt3, (u16*)bufA, 1);
  // 6: agg(L3, no relu) -> bufB
  agg_k<<<AB, 256, 0, stream>>>(bufA, dinv, rowptr, colarr, b3, bufB);
  // 7: pooling
  pool_k<<<N_GRAPHS, 256, 0, stream>>>(bufB, batch, flag, out);
}

// Round 10
// 418.873 us; speedup vs baseline: 1.0429x; 1.0429x over previous
//
#include <hip/hip_runtime.h>
#include <stdint.h>

typedef unsigned short u16;
typedef unsigned int   u32;

#define N_NODES  100000
#define N_EDGES  1600000
#define DFEAT    128
#define N_GRAPHS 512

#define NBKT   391    // buckets of 256 nodes (ceil(N/256))
#define EPB    8192   // edges per block in hist/scatter
#define NBLK_E 196    // ceil(N_EDGES/EPB)
#define LBUF   8192   // per-bucket capacity (mean 4096, sigma ~64)
#define GB1    1563   // gemm1 blocks (64 rows each)

typedef float f32x4 __attribute__((ext_vector_type(4)));
typedef short s16x8 __attribute__((ext_vector_type(8)));

__device__ __forceinline__ float bflo(u32 u) { return __uint_as_float(u << 16); }
__device__ __forceinline__ float bfhi(u32 u) { return __uint_as_float(u & 0xffff0000u); }
__device__ __forceinline__ u16 f2bf(float f) {
  u32 u = __float_as_uint(f);
  return (u16)((u + 0x7fffu + ((u >> 16) & 1u)) >> 16);   // RNE
}
__device__ __forceinline__ u32 pack2(float f0, float f1) {
  return (u32)f2bf(f0) | ((u32)f2bf(f1) << 16);
}

__device__ __forceinline__ int ld_src(const int* ei, int m, int e) {
  return m ? ei[2 * e] : ei[e];
}
__device__ __forceinline__ int ld_dst(const int* ei, int m, int e) {
  return m ? ei[2 * (N_EDGES + e)] : ei[N_EDGES + e];
}

// block-local int64-vs-int32 detect (odd words of first 64 edge slots all zero <=> int64)
__device__ __forceinline__ int detect_m_block(const int* __restrict__ ei, int* sm) {
  int t = threadIdx.x;
  if (t < 64) {
    int v = ei[2 * t + 1];
    unsigned long long b = __ballot(v != 0);
    if (t == 0) *sm = (b == 0ull) ? 1 : 0;
  }
  __syncthreads();
  return *sm;
}

#define LP 136   // LDS pitch in ushorts (272B, 16B-aligned rows)

// ---------------- mega pass: gemm1 (64-row tiles, unscaled) + histogram + W cvt + flag
// LDS overlay: gemm branch uses sX(64*LP)+sW(128*LP)=52.2KB; hist branch aliases sX.
__global__ __launch_bounds__(256) void mega_k(const float* __restrict__ x,
                                              const int* __restrict__ ei,
                                              int* __restrict__ ghist,   // [k*NBLK_E + b2]
                                              const float* __restrict__ W1,
                                              const float* __restrict__ W2,
                                              const float* __restrict__ W3,
                                              u16* __restrict__ T2, u16* __restrict__ T3,
                                              int* __restrict__ flag,
                                              u16* __restrict__ Y) {
  __shared__ char smem[(64 + 128) * LP * 2];
  u16* sX = (u16*)smem;
  u16* sW = (u16*)(smem + 64 * LP * 2);
  int* hist = (int*)smem;                    // alias (hist branch only)
  __shared__ int sm;
  int tid = threadIdx.x, b = blockIdx.x;

  if (b < GB1) {
    // ---- gemm1: Y = bf16(X @ W1), unscaled (dinv not ready yet) ----
    int r0 = b * 64;
    // stage W1 transpose+convert: sW[n*LP + k] = bf16(W1[k][n])
    for (int c = tid; c < 2048; c += 256) {
      int n = c & 127, k0 = (c >> 7) * 8;
#pragma unroll
      for (int j = 0; j < 8; j++)
        sW[n * LP + k0 + j] = f2bf(W1[(size_t)(k0 + j) * DFEAT + n]);
    }
    // stage X f32 -> bf16 (64 rows)
    for (int c = tid; c < 1024; c += 256) {
      int row = c >> 4, off = (c & 15) * 8;
      int grow = r0 + row;
      uint4 o = make_uint4(0, 0, 0, 0);
      if (grow < N_NODES) {
        const float* px = x + (size_t)grow * DFEAT + off;
        float4 v0 = *(const float4*)px;
        float4 v1 = *(const float4*)(px + 4);
        o.x = pack2(v0.x, v0.y); o.y = pack2(v0.z, v0.w);
        o.z = pack2(v1.x, v1.y); o.w = pack2(v1.z, v1.w);
      }
      *(uint4*)(&sX[row * LP + off]) = o;
    }
    __syncthreads();

    int wave = tid >> 6, lane = tid & 63;
    int q = lane >> 4, r = lane & 15;
    int wr0 = wave * 16;

    f32x4 acc[8];
#pragma unroll
    for (int i = 0; i < 8; i++) acc[i] = (f32x4){0.f, 0.f, 0.f, 0.f};

#pragma unroll
    for (int kk = 0; kk < 4; kk++) {
      int k0 = kk * 32;
      s16x8 a = *(const s16x8*)(&sX[(wr0 + r) * LP + k0 + q * 8]);
#pragma unroll
      for (int nt = 0; nt < 8; nt++) {
        s16x8 bb = *(const s16x8*)(&sW[(nt * 16 + r) * LP + k0 + q * 8]);
        acc[nt] = __builtin_amdgcn_mfma_f32_16x16x32_bf16(a, bb, acc[nt], 0, 0, 0);
      }
    }

#pragma unroll
    for (int i = 0; i < 4; i++) {
      int grow = r0 + wr0 + q * 4 + i;
      if (grow < N_NODES) {
#pragma unroll
        for (int nt = 0; nt < 8; nt++)
          Y[(size_t)grow * DFEAT + nt * 16 + r] = f2bf(acc[nt][i]);
      }
    }
    return;
  }

  if (b < GB1 + NBLK_E) {
    // ---- edge histogram over buckets (k-major ghist) ----
    int hb = b - GB1;
    int m = detect_m_block(ei, &sm);
    for (int i = tid; i < NBKT; i += 256) hist[i] = 0;
    __syncthreads();
    int e0 = hb * EPB;
#pragma unroll
    for (int p = 0; p < EPB / 256; p++) {
      int e = e0 + p * 256 + tid;
      if (e < N_EDGES) atomicAdd(&hist[ld_dst(ei, m, e) >> 8], 1);
    }
    __syncthreads();
    for (int i = tid; i < NBKT; i += 256) ghist[(size_t)i * NBLK_E + hb] = hist[i];
    return;
  }

  int r = b - GB1 - NBLK_E;
  if (r < 2) {   // W2/W3 transpose+convert
    const float* W = (r == 0) ? W2 : W3;
    u16* T         = (r == 0) ? T2 : T3;
    for (int i = tid; i < DFEAT * DFEAT; i += 256) {
      int n = i >> 7, k = i & 127;
      T[i] = f2bf(W[k * DFEAT + n]);
    }
  } else {       // flag for pool_k
    if (tid < 64) {
      int v = ei[2 * tid + 1];
      unsigned long long mm = __ballot(v != 0);
      if (tid == 0) *flag = (mm == 0ull) ? 1 : 0;
    }
  }
}

// exclusive scan of LDS array arr[NBKT] -> bb[NBKT+1] (256 threads)
__device__ __forceinline__ void scan_lds391(const int* arr, int* bb, int* sc) {
  int t = threadIdx.x;
  int v0 = arr[t];
  sc[t] = v0;
  for (int off = 1; off < 256; off <<= 1) {
    __syncthreads(); int add = (t >= off) ? sc[t - off] : 0;
    __syncthreads(); sc[t] += add;
  }
  __syncthreads();
  bb[t] = sc[t] - v0;
  int base256 = sc[255];
  __syncthreads();
  int v1 = (t < NBKT - 256) ? arr[256 + t] : 0;
  sc[t] = v1;
  for (int off = 1; off < 256; off <<= 1) {
    __syncthreads(); int add = (t >= off) ? sc[t - off] : 0;
    __syncthreads(); sc[t] += add;
  }
  __syncthreads();
  if (t < NBKT - 256) bb[256 + t] = base256 + sc[t] - v1;
  if (t == 0) bb[NBKT] = N_EDGES;
  __syncthreads();
}

// ---------------- pass C: place edges into bucket regions (k-major inline prefix) ----
__global__ __launch_bounds__(256) void scatterC_k(const int* __restrict__ ei,
                                                  const int* __restrict__ ghist,
                                                  u32* __restrict__ colpk) {
  __shared__ int sm;
  __shared__ int colsum[NBKT];
  __shared__ int colpre[NBKT];
  __shared__ int cur[NBKT];
  __shared__ int bb[NBKT + 1];
  __shared__ int sc[256];
  int t = threadIdx.x, b = blockIdx.x;
  int m = detect_m_block(ei, &sm);
  // contiguous per-k row of ghist: totals + prefix over blocks < b
  for (int k = t; k < NBKT; k += 256) {
    const int* row = ghist + (size_t)k * NBLK_E;
    int tot = 0, pre = 0;
    for (int b2 = 0; b2 < NBLK_E; b2++) {
      int v = row[b2];
      tot += v;
      pre += (b2 < b) ? v : 0;
    }
    colsum[k] = tot; colpre[k] = pre;
  }
  __syncthreads();
  scan_lds391(colsum, bb, sc);
  for (int k = t; k < NBKT; k += 256) cur[k] = bb[k] + colpre[k];
  __syncthreads();
  int e0 = b * EPB;
#pragma unroll
  for (int p = 0; p < EPB / 256; p++) {
    int e = e0 + p * 256 + t;
    if (e < N_EDGES) {
      int d = ld_dst(ei, m, e);
      int s = ld_src(ei, m, e);
      int pos = atomicAdd(&cur[d >> 8], 1);
      colpk[pos] = (u32)s | ((u32)(d & 255) << 24);
    }
  }
}

// ---------------- pass D: degrees, rowptr, dinv, exact CSR placement ----------------
__global__ __launch_bounds__(256) void fillD_k(const int* __restrict__ ghist,
                                               const u32* __restrict__ colpk,
                                               int* __restrict__ colarr,
                                               int* __restrict__ rowptr,
                                               float* __restrict__ dinv) {
  __shared__ int hist[256];
  __shared__ int cur[256];
  __shared__ int lbuf[LBUF];
  __shared__ int colsum[NBKT];
  __shared__ int bb[NBKT + 1];
  __shared__ int sc[256];
  int t = threadIdx.x, b = blockIdx.x;
  for (int k = t; k < NBKT; k += 256) {
    const int* row = ghist + (size_t)k * NBLK_E;
    int tot = 0;
    for (int b2 = 0; b2 < NBLK_E; b2++) tot += row[b2];
    colsum[k] = tot;
  }
  __syncthreads();
  scan_lds391(colsum, bb, sc);
  int base = bb[b], end = bb[b + 1], cnt = end - base;
  hist[t] = 0;
  __syncthreads();
  for (int i = t; i < cnt; i += 256) atomicAdd(&hist[colpk[base + i] >> 24], 1);
  __syncthreads();
  int c = hist[t];
  cur[t] = c;
  for (int off = 1; off < 256; off <<= 1) {
    __syncthreads(); int add = (t >= off) ? cur[t - off] : 0;
    __syncthreads(); cur[t] += add;
  }
  __syncthreads();
  int excl = cur[t] - c;
  int node = b * 256 + t;
  if (node < N_NODES) {
    rowptr[node] = base + excl;
    dinv[node] = rsqrtf((float)(c + 1));      // +1 self-loop
  }
  if (b == NBKT - 1 && t == 0) rowptr[N_NODES] = N_EDGES;
  __syncthreads();
  cur[t] = excl;
  __syncthreads();
  for (int i = t; i < cnt; i += 256) {
    u32 v = colpk[base + i];
    int slot = atomicAdd(&cur[v >> 24], 1);
    if (slot < LBUF) lbuf[slot] = (int)(v & 0x00FFFFFFu);
  }
  __syncthreads();
  for (int i = t; i < cnt; i += 256) colarr[base + i] = lbuf[i];
}

// ---------------- gather-accumulate ----------------
struct Acc8 {
  float a0, a1, a2, a3, a4, a5, a6, a7;
  __device__ __forceinline__ void zero() {
    a0 = a1 = a2 = a3 = a4 = a5 = a6 = a7 = 0.f;
  }
  __device__ __forceinline__ void addv(uint4 v) {
    a0 += bflo(v.x); a1 += bfhi(v.x); a2 += bflo(v.y); a3 += bfhi(v.y);
    a4 += bflo(v.z); a5 += bfhi(v.z); a6 += bflo(v.w); a7 += bfhi(v.w);
  }
  __device__ __forceinline__ void fmav(uint4 v, float s) {
    a0 = fmaf(bflo(v.x), s, a0); a1 = fmaf(bfhi(v.x), s, a1);
    a2 = fmaf(bflo(v.y), s, a2); a3 = fmaf(bfhi(v.y), s, a3);
    a4 = fmaf(bflo(v.z), s, a4); a5 = fmaf(bfhi(v.z), s, a5);
    a6 = fmaf(bflo(v.w), s, a6); a7 = fmaf(bfhi(v.w), s, a7);
  }
};

__device__ __forceinline__ Acc8 gather_plain(const u32* __restrict__ HS,
                                             int s, int e, int node, int fp,
                                             const int* __restrict__ colidx) {
  Acc8 A; A.zero();
  A.addv(*(const uint4*)(HS + (size_t)node * 64 + fp * 4));
  int j = s;
  for (; j + 4 <= e; j += 4) {
    int i0 = colidx[j], i1 = colidx[j + 1], i2 = colidx[j + 2], i3 = colidx[j + 3];
    uint4 w0 = *(const uint4*)(HS + (size_t)i0 * 64 + fp * 4);
    uint4 w1 = *(const uint4*)(HS + (size_t)i1 * 64 + fp * 4);
    uint4 w2 = *(const uint4*)(HS + (size_t)i2 * 64 + fp * 4);
    uint4 w3 = *(const uint4*)(HS + (size_t)i3 * 64 + fp * 4);
    A.addv(w0); A.addv(w1); A.addv(w2); A.addv(w3);
  }
  for (; j < e; j++) {
    A.addv(*(const uint4*)(HS + (size_t)colidx[j] * 64 + fp * 4));
  }
  return A;
}

__device__ __forceinline__ Acc8 gather_scaled(const u32* __restrict__ HS,
                                              const float* __restrict__ dinv,
                                              int s, int e, int node, int fp,
                                              const int* __restrict__ colidx) {
  Acc8 A; A.zero();
  A.fmav(*(const uint4*)(HS + (size_t)node * 64 + fp * 4), dinv[node]);
  int j = s;
  for (; j + 4 <= e; j += 4) {
    int i0 = colidx[j], i1 = colidx[j + 1], i2 = colidx[j + 2], i3 = colidx[j + 3];
    float s0 = dinv[i0], s1 = dinv[i1], s2 = dinv[i2], s3 = dinv[i3];
    uint4 w0 = *(const uint4*)(HS + (size_t)i0 * 64 + fp * 4);
    uint4 w1 = *(const uint4*)(HS + (size_t)i1 * 64 + fp * 4);
    uint4 w2 = *(const uint4*)(HS + (size_t)i2 * 64 + fp * 4);
    uint4 w3 = *(const uint4*)(HS + (size_t)i3 * 64 + fp * 4);
    A.fmav(w0, s0); A.fmav(w1, s1); A.fmav(w2, s2); A.fmav(w3, s3);
  }
  for (; j < e; j++) {
    int i0 = colidx[j];
    A.fmav(*(const uint4*)(HS + (size_t)i0 * 64 + fp * 4), dinv[i0]);
  }
  return A;
}

// ---------------- fused agg(layer i) + row-GEMM(layer i+1) ----------------
__global__ __launch_bounds__(256) void aggmm_k(const u32* __restrict__ HS,
                                               const float* __restrict__ dinv,
                                               const int* __restrict__ rowptr,
                                               const int* __restrict__ colidx,
                                               const float* __restrict__ bias,
                                               const u16* __restrict__ Wt,
                                               u16* __restrict__ Y,
                                               int src_scaled) {
  __shared__ u16 sX[16 * LP];
  int t = threadIdx.x;
  int r0b = blockIdx.x * 16;     // grid 6250 -> exactly N_NODES
  int lrow = t >> 4, fp = t & 15;
  int node = r0b + lrow;
  int s = rowptr[node], e = rowptr[node + 1];

  Acc8 A;
  if (src_scaled) A = gather_plain(HS, s, e, node, fp, colidx);
  else            A = gather_scaled(HS, dinv, s, e, node, fp, colidx);

  float dv = dinv[node];
  float4 b0 = *(const float4*)(bias + fp * 8);
  float4 b1 = *(const float4*)(bias + fp * 8 + 4);
  float r0f = fmaxf(A.a0 * dv + b0.x, 0.f), r1f = fmaxf(A.a1 * dv + b0.y, 0.f);
  float r2f = fmaxf(A.a2 * dv + b0.z, 0.f), r3f = fmaxf(A.a3 * dv + b0.w, 0.f);
  float r4f = fmaxf(A.a4 * dv + b1.x, 0.f), r5f = fmaxf(A.a5 * dv + b1.y, 0.f);
  float r6f = fmaxf(A.a6 * dv + b1.z, 0.f), r7f = fmaxf(A.a7 * dv + b1.w, 0.f);
  uint4 o;
  o.x = pack2(r0f, r1f); o.y = pack2(r2f, r3f);
  o.z = pack2(r4f, r5f); o.w = pack2(r6f, r7f);
  *(uint4*)(&sX[lrow * LP + fp * 8]) = o;
  __syncthreads();

  // row-GEMM: 16 rows x 128 cols, K=128; each wave 2 N-tiles; B from global (L1-hot)
  int wave = t >> 6, lane = t & 63;
  int q = lane >> 4, r = lane & 15;
  int nt0 = wave * 2, nt1 = wave * 2 + 1;

  f32x4 acc0 = (f32x4){0.f, 0.f, 0.f, 0.f};
  f32x4 acc1 = (f32x4){0.f, 0.f, 0.f, 0.f};
#pragma unroll
  for (int kk = 0; kk < 4; kk++) {
    int k0 = kk * 32;
    s16x8 a  = *(const s16x8*)(&sX[r * LP + k0 + q * 8]);
    s16x8 w0 = *(const s16x8*)(Wt + (size_t)(nt0 * 16 + r) * DFEAT + k0 + q * 8);
    s16x8 w1 = *(const s16x8*)(Wt + (size_t)(nt1 * 16 + r) * DFEAT + k0 + q * 8);
    acc0 = __builtin_amdgcn_mfma_f32_16x16x32_bf16(a, w0, acc0, 0, 0, 0);
    acc1 = __builtin_amdgcn_mfma_f32_16x16x32_bf16(a, w1, acc1, 0, 0, 0);
  }
#pragma unroll
  for (int i = 0; i < 4; i++) {
    int grow = r0b + q * 4 + i;
    float dvv = dinv[grow];
    Y[(size_t)grow * DFEAT + nt0 * 16 + r] = f2bf(acc0[i] * dvv);
    Y[(size_t)grow * DFEAT + nt1 * 16 + r] = f2bf(acc1[i] * dvv);
  }
}

// ---------------- standalone aggregation (layer-3 epilogue) ----------------
__global__ __launch_bounds__(256) void agg_k(const u32* __restrict__ HS,
                                             const float* __restrict__ dinv,
                                             const int* __restrict__ rowptr,
                                             const int* __restrict__ colidx,
                                             const float* __restrict__ bias,
                                             u32* __restrict__ OUT) {
  int t = threadIdx.x;
  int node = blockIdx.x * 16 + (t >> 4);   // grid 6250 -> exactly N_NODES
  int fp = t & 15;
  int s = rowptr[node], e = rowptr[node + 1];

  Acc8 A = gather_plain(HS, s, e, node, fp, colidx);

  float dv = dinv[node];
  float4 b0 = *(const float4*)(bias + fp * 8);
  float4 b1 = *(const float4*)(bias + fp * 8 + 4);
  uint4 o;
  o.x = pack2(A.a0 * dv + b0.x, A.a1 * dv + b0.y);
  o.y = pack2(A.a2 * dv + b0.z, A.a3 * dv + b0.w);
  o.z = pack2(A.a4 * dv + b1.x, A.a5 * dv + b1.y);
  o.w = pack2(A.a6 * dv + b1.z, A.a7 * dv + b1.w);
  *(uint4*)(OUT + (size_t)node * 64 + fp * 4) = o;
}

// ---------------- pooling: mean over sorted batch ranges ----------------
__device__ __forceinline__ int lower_bound_i(const int* a, int n, int key, int shift) {
  int lo = 0, hi = n;
  while (lo < hi) {
    int mid = (lo + hi) >> 1;
    if (a[mid << shift] < key) lo = mid + 1; else hi = mid;
  }
  return lo;
}

__global__ __launch_bounds__(256) void pool_k(const u32* __restrict__ H,
                                              const int* __restrict__ batch,
                                              const int* __restrict__ flag,
                                              float* __restrict__ OUT) {
  int g = blockIdx.x;
  int m = *flag;   // 1 if int64 batch
  int lo = lower_bound_i(batch, N_NODES, g, m);
  int hi = lower_bound_i(batch, N_NODES, g + 1, m);
  int cnt = hi - lo;
  int d2 = threadIdx.x & 63;
  int half = threadIdx.x >> 6;
  float a0 = 0.f, a1 = 0.f;
  for (int row = lo + half; row < hi; row += 4) {
    u32 v = H[(size_t)row * 64 + d2];
    a0 += bflo(v); a1 += bfhi(v);
  }
  __shared__ float red0[256], red1[256];
  red0[threadIdx.x] = a0; red1[threadIdx.x] = a1;
  __syncthreads();
  if (threadIdx.x < 64) {
    float s0 = red0[d2] + red0[d2 + 64] + red0[d2 + 128] + red0[d2 + 192];
    float s1 = red1[d2] + red1[d2 + 64] + red1[d2 + 128] + red1[d2 + 192];
    float inv = 1.0f / fmaxf((float)cnt, 1.0f);
    OUT[g * DFEAT + 2 * d2]     = s0 * inv;
    OUT[g * DFEAT + 2 * d2 + 1] = s1 * inv;
  }
}

// ---------------- orchestration (7 dispatches) ----------------

extern "C" void kernel_launch(void* const* d_in, const int* in_sizes, int n_in,
                              void* d_out, int out_size, void* d_ws, size_t ws_size,
                              hipStream_t stream) {
  const float* x   = (const float*)d_in[0];
  const int* ei    = (const int*)d_in[1];
  const int* batch = (const int*)d_in[2];
  const float* W1  = (const float*)d_in[3];
  const float* b1  = (const float*)d_in[4];
  const float* W2  = (const float*)d_in[5];
  const float* b2  = (const float*)d_in[6];
  const float* W3  = (const float*)d_in[7];
  const float* b3  = (const float*)d_in[8];
  float* out = (float*)d_out;

  char* p = (char*)d_ws;
  size_t off = 0;
  auto carve = [&](size_t bytes) -> void* {
    void* q = p + off;
    off = (off + bytes + 255) & ~(size_t)255;
    return q;
  };
  int*   flag   = (int*)carve(256);
  int*   ghist  = (int*)carve((size_t)NBKT * NBLK_E * 4);  // k-major
  int*   rowptr = (int*)carve((N_NODES + 1) * 4);
  float* dinv   = (float*)carve(N_NODES * 4);
  u32*   colpk  = (u32*)carve((size_t)N_EDGES * 4);
  int*   colarr = (int*)carve((size_t)N_EDGES * 4);
  u16*   Wt2    = (u16*)carve(DFEAT * DFEAT * 2);
  u16*   Wt3    = (u16*)carve(DFEAT * DFEAT * 2);
  u32*   bufA   = (u32*)carve((size_t)N_NODES * 64 * 4);
  u32*   bufB   = (u32*)carve((size_t)N_NODES * 64 * 4);
  (void)ws_size;

  const int AB = N_NODES / 16;            // 6250

  // 1: gemm1(X@W1, unscaled, 64-row tiles) + histogram + W2/W3 cvt + flag
  mega_k<<<GB1 + NBLK_E + 3, 256, 0, stream>>>(x, ei, ghist, W1, W2, W3, Wt2, Wt3,
                                               flag, (u16*)bufA);
  // 2: bucket scatter (k-major inline prefix)
  scatterC_k<<<NBLK_E, 256, 0, stream>>>(ei, ghist, colpk);
  // 3: CSR finalize + degrees + dinv
  fillD_k<<<NBKT, 256, 0, stream>>>(ghist, colpk, colarr, rowptr, dinv);
  // 4: agg(L1, src-scaled gather) + relu + row-GEMM W2 -> bufB (dinv-scaled)
  aggmm_k<<<AB, 256, 0, stream>>>(bufA, dinv, rowptr, colarr, b1, Wt2, (u16*)bufB, 0);
  // 5: agg(L2) + relu + row-GEMM W3 -> bufA (dinv-scaled)
  aggmm_k<<<AB, 256, 0, stream>>>(bufB, dinv, rowptr, colarr, b2, Wt3, (u16*)bufA, 1);
  // 6: agg(L3, no relu) -> bufB
  agg_k<<<AB, 256, 0, stream>>>(bufA, dinv, rowptr, colarr, b3, bufB);
  // 7: pooling
  pool_k<<<N_GRAPHS, 256, 0, stream>>>(bufB, batch, flag, out);
}